// Round 6
// baseline (885.430 us; speedup 1.0000x reference)
//
#include <hip/hip_runtime.h>
#include <stdint.h>

#define B_ 8
#define L_ 2500
#define D_ 512
#define Y_ 8921
#define LP 2560   // padded L = 20*128
#define YP 8960   // padded Y = 140*64
#define YT 64     // y-tile per block
#define BLK 128   // l-tile
#define BK 32
#define NKT 16    // 512/32
#define NS 4      // l-splits
#define LTS 5     // l-tiles of 128 per split (20/NS)
#define NYT 140   // YP/YT
#define NBLK (NYT * B_ * NS)  // 4480 blocks
#define PERX (NBLK / 8)       // 560 work items per XCD

typedef float f32x4 __attribute__((ext_vector_type(4)));
typedef __bf16 bf16x8 __attribute__((ext_vector_type(8)));
typedef unsigned short u16;
typedef unsigned int u32;

// ---- f32 -> bf16 (RTNE) pack helpers ----
__device__ __forceinline__ u32 pack2(float a, float b) {
  u32 ua = __float_as_uint(a); ua = (ua + 0x7FFFu + ((ua >> 16) & 1u)) >> 16;
  u32 ub = __float_as_uint(b); ub = (ub + 0x7FFFu + ((ub >> 16) & 1u)) >> 16;
  return ua | (ub << 16);
}

// x [B,L,D] f32 -> [B,LP,D] bf16 (pad rows zero)
__global__ void cvt_x_kernel(const float* __restrict__ x, u16* __restrict__ xb) {
  int idx = blockIdx.x * 256 + threadIdx.x;   // one 8-elem chunk
  int row = idx >> 6;                         // b*LP + l
  int c8  = (idx & 63) << 3;
  int b = row / LP;
  int l = row - b * LP;
  uint4 o;
  if (l < L_) {
    const float* s = x + (size_t)(b * L_ + l) * D_ + c8;
    float4 f0 = *(const float4*)s;
    float4 f1 = *(const float4*)(s + 4);
    o.x = pack2(f0.x, f0.y); o.y = pack2(f0.z, f0.w);
    o.z = pack2(f1.x, f1.y); o.w = pack2(f1.z, f1.w);
  } else {
    o = make_uint4(0u, 0u, 0u, 0u);
  }
  *(uint4*)(xb + (size_t)row * D_ + c8) = o;
}

// U,Wf [Y,D] f32 -> [YP,D] bf16 each (pad rows zero)
__global__ void cvt_w_kernel(const float* __restrict__ U, const float* __restrict__ Wf,
                             u16* __restrict__ Ub, u16* __restrict__ Wb) {
  int idx = blockIdx.x * 256 + threadIdx.x;
  const int half = YP * 64;
  const float* src = U; u16* dst = Ub;
  int i = idx;
  if (idx >= half) { i -= half; src = Wf; dst = Wb; }
  int row = i >> 6;
  int c8  = (i & 63) << 3;
  uint4 o;
  if (row < Y_) {
    const float* s = src + (size_t)row * D_ + c8;
    float4 f0 = *(const float4*)s;
    float4 f1 = *(const float4*)(s + 4);
    o.x = pack2(f0.x, f0.y); o.y = pack2(f0.z, f0.w);
    o.z = pack2(f1.x, f1.y); o.w = pack2(f1.z, f1.w);
  } else {
    o = make_uint4(0u, 0u, 0u, 0u);
  }
  *(uint4*)(dst + (size_t)row * D_ + c8) = o;
}

__device__ __forceinline__ void async16(const u16* g, u16* l) {
  __builtin_amdgcn_global_load_lds(
      (const __attribute__((address_space(1))) u32*)g,
      (__attribute__((address_space(3))) u32*)l, 16, 0, 0);
}

// Fused per (y-tile 64, b, l-split): stream LTS l-tiles of 128, MFMA att & s,
// per-lane online softmax (cross-lane + cross-half merge at kernel end).
//
// Occupancy is the wall (R0-R5: 2 wave-streams/SIMD, MfmaUtil pinned ~31%).
// Wave pair split: wv>>1 owns 32 y-rows, wv&1 owns an l-column half (4 of 8
// cl-groups). Accumulators 64 f32/lane (vs 128) -> ~150 unified regs ->
// 3 independent blocks/SIMD at launch_bounds(256,3). Same steps/block, same
// per-y-row A-frag traffic, same LDS-read-per-MFMA as R5.
//
// Partial layout: part[((b*140 + yt)*NS + s)*192 + {0,64,128} + ylocal]
__global__ __launch_bounds__(256, 3) void fused_kernel(
    const u16* __restrict__ xb,   // [B][LP][D] bf16
    const u16* __restrict__ Ub,   // [YP][D]
    const u16* __restrict__ Wb,   // [YP][D]
    float* __restrict__ part)
{
  __shared__ __align__(16) u16 sX[BLK * BK];   // one [128][32] slice, 8 KB
  __shared__ float sMZW[3 * YT];               // cross-half merge buffer

  const int t    = threadIdx.x;
  const int lane = t & 63;
  const int wv   = t >> 6;          // wave 0..3
  const int wv2  = wv >> 1;         // owns y rows [wv2*32, wv2*32+32)
  const int ch   = wv & 1;          // l-column half: cl-groups [ch*4, ch*4+4)
  const int l16  = lane & 15;
  const int q    = lane >> 4;       // quad 0..3

  // XCD-contiguous work id: bid%8 = XCD (round-robin dispatch); yt slow per XCD
  const int bid = blockIdx.x;
  const int w   = (bid & 7) * PERX + (bid >> 3);
  const int yt  = w >> 5;           // 0..139
  const int rem = w & 31;
  const int b   = rem >> 2;         // 0..7
  const int s   = rem & 3;          // l-split 0..3
  const int y0  = yt * YT;

  // X staging: thread t loads 16B chunk: row = t>>2 (+64 for 2nd op), chunk (t&3)*8
  const int srow = t >> 2;
  const int scol = (t & 3) << 3;
  const u16* gXb = xb + (size_t)b * LP * D_ + (size_t)srow * D_ + scol;
  u16* lX0 = sX + t * 8;            // rows 0..63
  u16* lX1 = sX + 2048 + t * 8;     // rows 64..127

  // A-fragment global pointers (per-lane): rows y0+wv2*32+l16 (+16), k chunk q*8.
  // Wave covers 16 rows x 64 B = 16 full cache lines per load op. L2-hot.
  const u16* fU0 = Ub + (size_t)(y0 + wv2 * 32 + l16) * D_ + q * 8;
  const u16* fU1 = fU0 + (size_t)16 * D_;
  const u16* fW0 = Wb + (size_t)(y0 + wv2 * 32 + l16) * D_ + q * 8;
  const u16* fW1 = fW0 + (size_t)16 * D_;

  // PER-LANE running softmax stats: lane covers cols ((ch*4+cl)*16+l16), cl=0..3,
  // for each of its 8 y-rows (si = ry*4+r).
  float M[8], Z[8], W[8];
#pragma unroll
  for (int i = 0; i < 8; ++i) { M[i] = -1e30f; Z[i] = 0.f; W[i] = 0.f; }

  const f32x4 z4 = {0.f, 0.f, 0.f, 0.f};

  for (int ltl = 0; ltl < LTS; ++ltl) {
    const int l0 = (s * LTS + ltl) * BLK;
    const u16* gX0 = gXb + (size_t)l0 * D_;
    const u16* gX1 = gX0 + (size_t)64 * D_;

    f32x4 accA[2][4], accS[2][4];
#pragma unroll
    for (int ry = 0; ry < 2; ++ry)
#pragma unroll
      for (int cl = 0; cl < 4; ++cl) { accA[ry][cl] = z4; accS[ry][cl] = z4; }

#pragma unroll 1
    for (int kt = 0; kt < NKT; ++kt) {
      const int ko = kt * BK;
      __syncthreads();                 // previous X slice consumed
      async16(gX0 + ko, lX0);
      async16(gX1 + ko, lX1);
      // A-frags global->VGPR between the barriers: latency overlaps DMA flight
      bf16x8 aU0 = *(const bf16x8*)(const void*)(fU0 + ko);
      bf16x8 aU1 = *(const bf16x8*)(const void*)(fU1 + ko);
      bf16x8 aW0 = *(const bf16x8*)(const void*)(fW0 + ko);
      bf16x8 aW1 = *(const bf16x8*)(const void*)(fW1 + ko);
      __syncthreads();                 // drains DMA + A-loads (vmcnt 0)

#pragma unroll
      for (int cl = 0; cl < 4; ++cl) {
        bf16x8 bX = *(const bf16x8*)(const void*)(sX + ((ch * 4 + cl) * 16 + l16) * BK + q * 8);
        accA[0][cl] = __builtin_amdgcn_mfma_f32_16x16x32_bf16(aU0, bX, accA[0][cl], 0, 0, 0);
        accA[1][cl] = __builtin_amdgcn_mfma_f32_16x16x32_bf16(aU1, bX, accA[1][cl], 0, 0, 0);
        accS[0][cl] = __builtin_amdgcn_mfma_f32_16x16x32_bf16(aW0, bX, accS[0][cl], 0, 0, 0);
        accS[1][cl] = __builtin_amdgcn_mfma_f32_16x16x32_bf16(aW1, bX, accS[1][cl], 0, 0, 0);
      }
    }

    // per-lane online softmax update. C/D: col(l)=lane&15, row(y)=q*4+reg
    const bool boundary = (l0 + BLK > L_);   // wave-uniform; 1 of 20 tiles
#pragma unroll
    for (int ry = 0; ry < 2; ++ry) {
#pragma unroll
      for (int r = 0; r < 4; ++r) {
        const int si = ry * 4 + r;
        float a[4];
        if (boundary) {
#pragma unroll
          for (int cl = 0; cl < 4; ++cl) {
            float v = accA[ry][cl][r];
            a[cl] = (l0 + (ch * 4 + cl) * 16 + l16 >= L_) ? -1e30f : v;
          }
        } else {
#pragma unroll
          for (int cl = 0; cl < 4; ++cl) a[cl] = accA[ry][cl][r];
        }
        float tmax = fmaxf(fmaxf(a[0], a[1]), fmaxf(a[2], a[3]));
        const float mnew  = fmaxf(M[si], tmax);
        const float scale = __expf(M[si] - mnew);
        float zl = 0.f, wl = 0.f;
#pragma unroll
        for (int cl = 0; cl < 4; ++cl) {
          float p = __expf(a[cl] - mnew);
          zl += p;
          wl = fmaf(p, accS[ry][cl][r], wl);
        }
        Z[si] = fmaf(Z[si], scale, zl);
        W[si] = fmaf(W[si], scale, wl);
        M[si] = mnew;
      }
    }
  }

  // cross-lane merge over the l16 group (butterfly with exp rescale)
#pragma unroll
  for (int si = 0; si < 8; ++si) {
    float M0 = M[si], Z0 = Z[si], W0 = W[si];
#pragma unroll
    for (int st = 1; st <= 8; st <<= 1) {
      const float Mo = __shfl_xor(M0, st);
      const float Zo = __shfl_xor(Z0, st);
      const float Wo = __shfl_xor(W0, st);
      const float mn = fmaxf(M0, Mo);
      const float sa = __expf(M0 - mn);
      const float sb = __expf(Mo - mn);
      Z0 = Z0 * sa + Zo * sb;
      W0 = W0 * sa + Wo * sb;
      M0 = mn;
    }
    M[si] = M0; Z[si] = Z0; W[si] = W0;
  }

  // cross-half merge (ch==1 publishes via LDS; ch==0 merges and writes part)
  __syncthreads();
  if (ch == 1 && l16 == 0) {
#pragma unroll
    for (int ry = 0; ry < 2; ++ry)
#pragma unroll
      for (int r = 0; r < 4; ++r) {
        const int si = ry * 4 + r;
        const int yl = wv2 * 32 + ry * 16 + q * 4 + r;
        sMZW[yl]            = M[si];
        sMZW[YT + yl]       = Z[si];
        sMZW[2 * YT + yl]   = W[si];
      }
  }
  __syncthreads();
  if (ch == 0 && l16 == 0) {
    float* p = part + ((size_t)(b * NYT + yt) * NS + s) * 192;
#pragma unroll
    for (int ry = 0; ry < 2; ++ry) {
#pragma unroll
      for (int r = 0; r < 4; ++r) {
        const int si = ry * 4 + r;
        const int yl = wv2 * 32 + ry * 16 + q * 4 + r;
        const float Mo = sMZW[yl];
        const float Zo = sMZW[YT + yl];
        const float Wo = sMZW[2 * YT + yl];
        const float mn = fmaxf(M[si], Mo);
        const float sa = __expf(M[si] - mn);
        const float sb = __expf(Mo - mn);
        p[yl]        = mn;
        p[64 + yl]   = Z[si] * sa + Zo * sb;
        p[128 + yl]  = W[si] * sa + Wo * sb;
      }
    }
  }
}

// Merge NS partials per (b,y); y = W/Z + bias; BCE partial -> atomicAdd.
__global__ void combine_kernel(const float* __restrict__ part,
                               const float* __restrict__ bias,
                               const float* __restrict__ target,
                               float* __restrict__ out) {
  const int idx = blockIdx.x * 256 + threadIdx.x;
  float lpart = 0.f;
  if (idx < B_ * Y_) {
    const int b = idx / Y_;
    const int y = idx - b * Y_;
    const int yt = y >> 6, yl = y & 63;
    const float* p = part + ((size_t)(b * NYT + yt) * NS) * 192 + yl;
    float M = -1e30f;
#pragma unroll
    for (int s2 = 0; s2 < NS; ++s2) M = fmaxf(M, p[s2 * 192]);
    float Z = 0.f, W = 0.f;
#pragma unroll
    for (int s2 = 0; s2 < NS; ++s2) {
      const float e = __expf(p[s2 * 192] - M);
      Z = fmaf(p[s2 * 192 + 64], e, Z);
      W = fmaf(p[s2 * 192 + 128], e, W);
    }
    const float yv = W / Z + bias[y];
    out[idx] = yv;
    const float tg = target[idx];
    lpart = fmaxf(yv, 0.f) - yv * tg + log1pf(__expf(-fabsf(yv)));
  }
  lpart += __shfl_xor(lpart, 1);  lpart += __shfl_xor(lpart, 2);
  lpart += __shfl_xor(lpart, 4);  lpart += __shfl_xor(lpart, 8);
  lpart += __shfl_xor(lpart, 16); lpart += __shfl_xor(lpart, 32);
  if ((threadIdx.x & 63) == 0)
    atomicAdd(out + (size_t)B_ * Y_, lpart * (1.0f / (B_ * Y_)));
}

extern "C" void kernel_launch(void* const* d_in, const int* in_sizes, int n_in,
                              void* d_out, int out_size, void* d_ws, size_t ws_size,
                              hipStream_t stream) {
  const float* x      = (const float*)d_in[0];
  const float* target = (const float*)d_in[1];
  // d_in[2] = text_inputs (unused by reference)
  const float* U      = (const float*)d_in[3];
  const float* Wf     = (const float*)d_in[4];
  const float* bias   = (const float*)d_in[5];
  float* out = (float*)d_out;

  u16* xb = (u16*)d_ws;                      // [B][LP][D]   20.97 MB
  u16* Ub = xb + (size_t)B_ * LP * D_;       // [YP][D]       9.18 MB
  u16* Wb = Ub + (size_t)YP * D_;            // [YP][D]       9.18 MB
  float* part = (float*)(Wb + (size_t)YP * D_);  // [B][140][NS][192] f32  3.44 MB

  hipMemsetAsync(out + (size_t)B_ * Y_, 0, sizeof(float), stream);
  cvt_x_kernel<<<dim3((B_ * LP * 64) / 256), 256, 0, stream>>>(x, xb);
  cvt_w_kernel<<<dim3((2 * YP * 64) / 256), 256, 0, stream>>>(U, Wf, Ub, Wb);
  fused_kernel<<<dim3(NBLK), 256, 0, stream>>>(xb, Ub, Wb, part);
  combine_kernel<<<dim3((B_ * Y_ + 255) / 256), 256, 0, stream>>>(part, bias, target, out);
}

// Round 7
// 573.952 us; speedup vs baseline: 1.5427x; 1.5427x over previous
//
#include <hip/hip_runtime.h>
#include <stdint.h>

#define B_ 8
#define L_ 2500
#define D_ 512
#define Y_ 8921
#define LP 2560   // padded L = 20*128
#define YP 8960   // padded Y = 70*128
#define BLK 128   // y-tile and l-tile
#define BK 32
#define NPAIR 4   // barrier-pairs per l-tile (each stages 4 k-slices = 128 k)
#define NS 4      // l-splits
#define LTS 5     // l-tiles of 128 per split (20/NS)
#define NBLK (70 * B_ * NS)   // 2240 blocks
#define PERX (NBLK / 8)       // 280 work items per XCD

typedef float f32x4 __attribute__((ext_vector_type(4)));
typedef __bf16 bf16x8 __attribute__((ext_vector_type(8)));
typedef unsigned short u16;
typedef unsigned int u32;

// ---- f32 -> bf16 (RTNE) pack helpers ----
__device__ __forceinline__ u32 pack2(float a, float b) {
  u32 ua = __float_as_uint(a); ua = (ua + 0x7FFFu + ((ua >> 16) & 1u)) >> 16;
  u32 ub = __float_as_uint(b); ub = (ub + 0x7FFFu + ((ub >> 16) & 1u)) >> 16;
  return ua | (ub << 16);
}

// x [B,L,D] f32 -> [B,LP,D] bf16 (pad rows zero)
__global__ void cvt_x_kernel(const float* __restrict__ x, u16* __restrict__ xb) {
  int idx = blockIdx.x * 256 + threadIdx.x;   // one 8-elem chunk
  int row = idx >> 6;                         // b*LP + l
  int c8  = (idx & 63) << 3;
  int b = row / LP;
  int l = row - b * LP;
  uint4 o;
  if (l < L_) {
    const float* s = x + (size_t)(b * L_ + l) * D_ + c8;
    float4 f0 = *(const float4*)s;
    float4 f1 = *(const float4*)(s + 4);
    o.x = pack2(f0.x, f0.y); o.y = pack2(f0.z, f0.w);
    o.z = pack2(f1.x, f1.y); o.w = pack2(f1.z, f1.w);
  } else {
    o = make_uint4(0u, 0u, 0u, 0u);
  }
  *(uint4*)(xb + (size_t)row * D_ + c8) = o;
}

// U,Wf [Y,D] f32 -> [YP,D] bf16 each (pad rows zero)
__global__ void cvt_w_kernel(const float* __restrict__ U, const float* __restrict__ Wf,
                             u16* __restrict__ Ub, u16* __restrict__ Wb) {
  int idx = blockIdx.x * 256 + threadIdx.x;
  const int half = YP * 64;
  const float* src = U; u16* dst = Ub;
  int i = idx;
  if (idx >= half) { i -= half; src = Wf; dst = Wb; }
  int row = i >> 6;
  int c8  = (i & 63) << 3;
  uint4 o;
  if (row < Y_) {
    const float* s = src + (size_t)row * D_ + c8;
    float4 f0 = *(const float4*)s;
    float4 f1 = *(const float4*)(s + 4);
    o.x = pack2(f0.x, f0.y); o.y = pack2(f0.z, f0.w);
    o.z = pack2(f1.x, f1.y); o.w = pack2(f1.z, f1.w);
  } else {
    o = make_uint4(0u, 0u, 0u, 0u);
  }
  *(uint4*)(dst + (size_t)row * D_ + c8) = o;
}

__device__ __forceinline__ void async16(const u16* g, u16* l) {
  __builtin_amdgcn_global_load_lds(
      (const __attribute__((address_space(1))) u32*)g,
      (__attribute__((address_space(3))) u32*)l, 16, 0, 0);
}

// Fused per (y-tile 128, b, l-split): stream LTS l-tiles of 128, MFMA att & s,
// per-lane online softmax (cross-lane merge once at kernel end).
//
// R0-R6 established: duration tracks BARRIER-PAIR COUNT (~fixed 1100-1700 cy
// overhead each), not staging bytes / vmcnt placement / occupancy. So: stage
// FOUR k-slices (128 k) per barrier-pair -> 20 pairs/block instead of 80,
// 128 MFMA/wave per pair. A-frags stay global->VGPR (R5, L2-hot via XCD
// swizzle); X via global_load_lds into 4x8KB slices (32 KB LDS).
// '#pragma unroll 1' on BOTH loops: no cross-iteration hoist, no spill (R4).
//
// Work-id swizzle: XCD k owns ids [k*280,(k+1)*280); yt slow within an XCD ->
// U/W slice reuse is L2-resident.
//
// Partial layout: part[((b*70 + yt)*NS + s)*384 + {0,128,256} + ylocal]
__global__ __launch_bounds__(256, 2) void fused_kernel(
    const u16* __restrict__ xb,   // [B][LP][D] bf16
    const u16* __restrict__ Ub,   // [YP][D]
    const u16* __restrict__ Wb,   // [YP][D]
    float* __restrict__ part)
{
  __shared__ __align__(16) u16 sX[4 * BLK * BK];   // four [128][32] slices, 32 KB

  const int t    = threadIdx.x;
  const int lane = t & 63;
  const int wv   = t >> 6;          // wave 0..3, owns y rows [wv*32, wv*32+32)
  const int l16  = lane & 15;
  const int q    = lane >> 4;       // quad 0..3

  // XCD-contiguous work id: bid%8 = XCD (round-robin dispatch)
  const int bid = blockIdx.x;
  const int w   = (bid & 7) * PERX + (bid >> 3);
  const int yt  = w >> 5;           // 0..69  (slow within an XCD)
  const int rem = w & 31;
  const int b   = rem >> 2;         // 0..7
  const int s   = rem & 3;          // l-split 0..3
  const int y0  = yt * BLK;

  // X staging: thread t loads 16B chunk: row = t>>2 (+64 for 2nd op), chunk (t&3)*8
  const int srow = t >> 2;
  const int scol = (t & 3) << 3;
  const u16* gXb = xb + (size_t)b * LP * D_ + (size_t)srow * D_ + scol;

  // A-fragment global pointers (per-lane): rows y0+wv*32+l16 (+16), k chunk q*8.
  // Wave covers 16 rows x 64 B = 16 full cache lines per load op. L2-hot.
  const u16* fU0 = Ub + (size_t)(y0 + wv * 32 + l16) * D_ + q * 8;
  const u16* fU1 = fU0 + (size_t)16 * D_;
  const u16* fW0 = Wb + (size_t)(y0 + wv * 32 + l16) * D_ + q * 8;
  const u16* fW1 = fW0 + (size_t)16 * D_;

  // PER-LANE running softmax stats: lane covers cols (cl*16+l16), cl=0..7,
  // for each of its 8 y-rows (si = ry*4+r).
  float M[8], Z[8], W[8];
#pragma unroll
  for (int i = 0; i < 8; ++i) { M[i] = -1e30f; Z[i] = 0.f; W[i] = 0.f; }

  const f32x4 z4 = {0.f, 0.f, 0.f, 0.f};

  for (int ltl = 0; ltl < LTS; ++ltl) {
    const int l0 = (s * LTS + ltl) * BLK;
    const u16* gX0 = gXb + (size_t)l0 * D_;
    const u16* gX1 = gX0 + (size_t)64 * D_;

    f32x4 accA[2][8], accS[2][8];
#pragma unroll
    for (int ry = 0; ry < 2; ++ry)
#pragma unroll
      for (int cl = 0; cl < 8; ++cl) { accA[ry][cl] = z4; accS[ry][cl] = z4; }

#pragma unroll 1
    for (int pair = 0; pair < NPAIR; ++pair) {
      const int pko = pair * 128;
      __syncthreads();                 // previous pair's slices consumed
      async16(gX0 + pko,      sX + t * 8);
      async16(gX1 + pko,      sX + 2048 + t * 8);
      async16(gX0 + pko + 32, sX + 4096 + t * 8);
      async16(gX1 + pko + 32, sX + 4096 + 2048 + t * 8);
      async16(gX0 + pko + 64, sX + 8192 + t * 8);
      async16(gX1 + pko + 64, sX + 8192 + 2048 + t * 8);
      async16(gX0 + pko + 96, sX + 12288 + t * 8);
      async16(gX1 + pko + 96, sX + 12288 + 2048 + t * 8);
      __syncthreads();                 // all 4 slices visible (vmcnt drain)

#pragma unroll 1
      for (int kk = 0; kk < 4; ++kk) {
        const int ko = pko + kk * BK;
        bf16x8 aU0 = *(const bf16x8*)(const void*)(fU0 + ko);
        bf16x8 aU1 = *(const bf16x8*)(const void*)(fU1 + ko);
        bf16x8 aW0 = *(const bf16x8*)(const void*)(fW0 + ko);
        bf16x8 aW1 = *(const bf16x8*)(const void*)(fW1 + ko);
        const u16* bXb = sX + kk * 4096;
#pragma unroll
        for (int cl = 0; cl < 8; ++cl) {
          bf16x8 bX = *(const bf16x8*)(const void*)(bXb + (cl * 16 + l16) * BK + q * 8);
          accA[0][cl] = __builtin_amdgcn_mfma_f32_16x16x32_bf16(aU0, bX, accA[0][cl], 0, 0, 0);
          accA[1][cl] = __builtin_amdgcn_mfma_f32_16x16x32_bf16(aU1, bX, accA[1][cl], 0, 0, 0);
          accS[0][cl] = __builtin_amdgcn_mfma_f32_16x16x32_bf16(aW0, bX, accS[0][cl], 0, 0, 0);
          accS[1][cl] = __builtin_amdgcn_mfma_f32_16x16x32_bf16(aW1, bX, accS[1][cl], 0, 0, 0);
        }
      }
    }

    // per-lane online softmax update. C/D: col(l)=lane&15, row(y)=q*4+reg
    const bool boundary = (l0 + BLK > L_);   // wave-uniform; 1 of 20 tiles
#pragma unroll
    for (int ry = 0; ry < 2; ++ry) {
#pragma unroll
      for (int r = 0; r < 4; ++r) {
        const int si = ry * 4 + r;
        float a[8];
        if (boundary) {
#pragma unroll
          for (int cl = 0; cl < 8; ++cl) {
            float v = accA[ry][cl][r];
            a[cl] = (l0 + cl * 16 + l16 >= L_) ? -1e30f : v;
          }
        } else {
#pragma unroll
          for (int cl = 0; cl < 8; ++cl) a[cl] = accA[ry][cl][r];
        }
        float tmax = a[0];
#pragma unroll
        for (int cl = 1; cl < 8; ++cl) tmax = fmaxf(tmax, a[cl]);
        const float mnew  = fmaxf(M[si], tmax);
        const float scale = __expf(M[si] - mnew);
        float zl = 0.f, wl = 0.f;
#pragma unroll
        for (int cl = 0; cl < 8; ++cl) {
          float p = __expf(a[cl] - mnew);
          zl += p;
          wl = fmaf(p, accS[ry][cl][r], wl);
        }
        Z[si] = fmaf(Z[si], scale, zl);
        W[si] = fmaf(W[si], scale, wl);
        M[si] = mnew;
      }
    }
  }

  // ONE cross-lane merge over the l16 group (butterfly with exp rescale)
#pragma unroll
  for (int si = 0; si < 8; ++si) {
    float M0 = M[si], Z0 = Z[si], W0 = W[si];
#pragma unroll
    for (int st = 1; st <= 8; st <<= 1) {
      const float Mo = __shfl_xor(M0, st);
      const float Zo = __shfl_xor(Z0, st);
      const float Wo = __shfl_xor(W0, st);
      const float mn = fmaxf(M0, Mo);
      const float sa = __expf(M0 - mn);
      const float sb = __expf(Mo - mn);
      Z0 = Z0 * sa + Zo * sb;
      W0 = W0 * sa + Wo * sb;
      M0 = mn;
    }
    M[si] = M0; Z[si] = Z0; W[si] = W0;
  }

  // write partial (M,Z,W) per owned y-row; stats now replicated -> l16==0 writes
  if (l16 == 0) {
    float* p = part + ((size_t)(b * 70 + yt) * NS + s) * 384;
#pragma unroll
    for (int ry = 0; ry < 2; ++ry) {
#pragma unroll
      for (int r = 0; r < 4; ++r) {
        const int si = ry * 4 + r;
        const int yl = wv * 32 + ry * 16 + q * 4 + r;
        p[yl]       = M[si];
        p[128 + yl] = Z[si];
        p[256 + yl] = W[si];
      }
    }
  }
}

// Merge NS partials per (b,y); y = W/Z + bias; BCE partial -> atomicAdd.
__global__ void combine_kernel(const float* __restrict__ part,
                               const float* __restrict__ bias,
                               const float* __restrict__ target,
                               float* __restrict__ out) {
  const int idx = blockIdx.x * 256 + threadIdx.x;
  float lpart = 0.f;
  if (idx < B_ * Y_) {
    const int b = idx / Y_;
    const int y = idx - b * Y_;
    const int yt = y >> 7, yl = y & 127;
    const float* p = part + ((size_t)(b * 70 + yt) * NS) * 384 + yl;
    float M = -1e30f;
#pragma unroll
    for (int s2 = 0; s2 < NS; ++s2) M = fmaxf(M, p[s2 * 384]);
    float Z = 0.f, W = 0.f;
#pragma unroll
    for (int s2 = 0; s2 < NS; ++s2) {
      const float e = __expf(p[s2 * 384] - M);
      Z = fmaf(p[s2 * 384 + 128], e, Z);
      W = fmaf(p[s2 * 384 + 256], e, W);
    }
    const float yv = W / Z + bias[y];
    out[idx] = yv;
    const float tg = target[idx];
    lpart = fmaxf(yv, 0.f) - yv * tg + log1pf(__expf(-fabsf(yv)));
  }
  lpart += __shfl_xor(lpart, 1);  lpart += __shfl_xor(lpart, 2);
  lpart += __shfl_xor(lpart, 4);  lpart += __shfl_xor(lpart, 8);
  lpart += __shfl_xor(lpart, 16); lpart += __shfl_xor(lpart, 32);
  if ((threadIdx.x & 63) == 0)
    atomicAdd(out + (size_t)B_ * Y_, lpart * (1.0f / (B_ * Y_)));
}

extern "C" void kernel_launch(void* const* d_in, const int* in_sizes, int n_in,
                              void* d_out, int out_size, void* d_ws, size_t ws_size,
                              hipStream_t stream) {
  const float* x      = (const float*)d_in[0];
  const float* target = (const float*)d_in[1];
  // d_in[2] = text_inputs (unused by reference)
  const float* U      = (const float*)d_in[3];
  const float* Wf     = (const float*)d_in[4];
  const float* bias   = (const float*)d_in[5];
  float* out = (float*)d_out;

  u16* xb = (u16*)d_ws;                      // [B][LP][D]   20.97 MB
  u16* Ub = xb + (size_t)B_ * LP * D_;       // [YP][D]       9.18 MB
  u16* Wb = Ub + (size_t)YP * D_;            // [YP][D]       9.18 MB
  float* part = (float*)(Wb + (size_t)YP * D_);  // [B][70][NS][384] f32  3.44 MB

  hipMemsetAsync(out + (size_t)B_ * Y_, 0, sizeof(float), stream);
  cvt_x_kernel<<<dim3((B_ * LP * 64) / 256), 256, 0, stream>>>(x, xb);
  cvt_w_kernel<<<dim3((2 * YP * 64) / 256), 256, 0, stream>>>(U, Wf, Ub, Wb);
  fused_kernel<<<dim3(NBLK), 256, 0, stream>>>(xb, Ub, Wb, part);
  combine_kernel<<<dim3((B_ * Y_ + 255) / 256), 256, 0, stream>>>(part, bias, target, out);
}